// Round 9
// baseline (456.065 us; speedup 1.0000x reference)
//
#include <hip/hip_runtime.h>
#include <hip/hip_bf16.h>

#define HID 128
#define NN 50000
#define NR 500
#define NE 625000
#define LRELU 0.01f
#define SCAN_BLOCKS 196   // ceil(NN/256)

typedef __hip_bfloat16 bf16;
typedef __attribute__((ext_vector_type(8))) short short8;
typedef __attribute__((ext_vector_type(4))) float float4_;

__device__ __forceinline__ float b2f(bf16 v) { return __bfloat162float(v); }
__device__ __forceinline__ bf16 f2b(float v) { return __float2bfloat16(v); }

__device__ __forceinline__ float san(float v) {
    return (v == v && v > -1e30f && v < 1e30f) ? v : 0.f;
}

// fast tanh: 1 - 2/(e^{2x}+1)
__device__ __forceinline__ float ftanh(float a) {
    float e = __expf(2.f * a);
    return 1.f - 2.f * __builtin_amdgcn_rcpf(e + 1.f);
}

__device__ __forceinline__ float ldf(const void* p, int i, int f32) {
    return f32 ? ((const float*)p)[i] : b2f(((const bf16*)p)[i]);
}
__device__ __forceinline__ void stf(void* p, int i, float v, int f32) {
    if (f32) ((float*)p)[i] = v;
    else ((bf16*)p)[i] = f2b(v);
}

__device__ __forceinline__ int clampi(int v, int hi) {
    return v < 0 ? 0 : (v >= hi ? hi - 1 : v);
}
__device__ __forceinline__ int idx_at(const int* p, int i, int is64) {
    return p[is64 ? (2 * i) : i];
}

__device__ __forceinline__ unsigned short bfbits(float v) {
    bf16 h = f2b(v);
    return *(unsigned short*)&h;
}
__device__ __forceinline__ unsigned int packbf2(float a, float b) {
    return (unsigned int)bfbits(a) | ((unsigned int)bfbits(b) << 16);
}
__device__ __forceinline__ float bflo(unsigned int u) { return __uint_as_float(u << 16); }
__device__ __forceinline__ float bfhi(unsigned int u) { return __uint_as_float(u & 0xffff0000u); }

__device__ __forceinline__ float xorReduce16(float v) {
    v += __shfl_xor(v, 1, 64);
    v += __shfl_xor(v, 2, 64);
    v += __shfl_xor(v, 4, 64);
    v += __shfl_xor(v, 8, 64);
    return v;
}
__device__ __forceinline__ float waveMax(float v) {
#pragma unroll
    for (int o = 1; o < 64; o <<= 1) v = fmaxf(v, __shfl_xor(v, o, 64));
    return v;
}
__device__ __forceinline__ float waveSum(float v) {
#pragma unroll
    for (int o = 1; o < 64; o <<= 1) v += __shfl_xor(v, o, 64);
    return v;
}

// ---------------------------------------------------------------- consolidated dtype detect
struct DetectArr {
    const void* p[16];
    int sz[16];
    int kind[16];
};

__global__ void detect_all(DetectArr d, int* __restrict__ flags) {
    int b = blockIdx.x;
    if (d.kind[b] == 1) {
        if (threadIdx.x == 0) {
            const int* q = (const int*)d.p[b];
            int o = 0;
            for (int i = 0; i < 64; ++i) o |= q[2 * i + 1];
            flags[b] = (o == 0) ? 1 : 0;
        }
        return;
    }
    __shared__ int sb[64], sf[64];
    const unsigned int* w = (const unsigned int*)d.p[b];
    int K = d.sz[b] >> 1;
    if (K > 4096) K = 4096;
    int bv = 0, fv = 0;
    for (int i = threadIdx.x; i < K; i += 64) {
        unsigned int x = w[i];
        unsigned int lo = x & 0xFFFFu, hi = x >> 16;
        if (lo == 0u) {
            if (hi) fv++;
        } else {
            unsigned int e = (lo >> 7) & 0xFFu;
            if (e >= 90u && e <= 160u) bv++;
            else fv++;
        }
    }
    sb[threadIdx.x] = bv; sf[threadIdx.x] = fv;
    __syncthreads();
    if (threadIdx.x == 0) {
        int B = 0, F = 0;
        for (int i = 0; i < 64; ++i) { B += sb[i]; F += sf[i]; }
        flags[b] = (F > B) ? 1 : 0;
    }
}

// ---------------------------------------------------------------- BN stats (blocks 0..127) + precomp (block 128)
__global__ void bn_pre(const void* __restrict__ r, const int* __restrict__ flags,
                       float* __restrict__ stats,
                       const void* __restrict__ Wmatt, const void* __restrict__ bmatt,
                       const void* __restrict__ qc,
                       const void* __restrict__ Wxatt, const void* __restrict__ bxatt,
                       const void* __restrict__ fq,
                       float* __restrict__ cmatt, float* __restrict__ cxatt) {
    __shared__ float sb[256], sq[256];
    int t = threadIdx.x;
    if (blockIdx.x == HID) {
        // precomp
        __shared__ float qcs[HID], fqs[HID];
        const int fWm = flags[8], fbm = flags[9], fqc = flags[2];
        const int fWx = flags[11], fbx = flags[12], ffq = flags[3];
        if (t < HID) {
            qcs[t] = ldf(qc, t, fqc);
            fqs[t] = ldf(fq, t, ffq);
        }
        __syncthreads();
        if (t < HID) {
            float a = ldf(bmatt, t, fbm), b = ldf(bxatt, t, fbx);
            for (int k = 0; k < HID; ++k) {
                a += ldf(Wmatt, t * 2 * HID + HID + k, fWm) * qcs[k];
                b += ldf(Wxatt, t * 2 * HID + HID + k, fWx) * fqs[k];
            }
            cmatt[t] = san(a);
            cxatt[t] = san(b);
        }
        return;
    }
    const int fr = flags[1];
    int h = blockIdx.x;
    float s = 0.f, ss = 0.f;
    for (int i = t; i < NR; i += 256) {
        float v = ldf(r, i * HID + h, fr);
        s += v; ss += v * v;
    }
    sb[t] = s; sq[t] = ss;
    __syncthreads();
    for (int o = 128; o > 0; o >>= 1) {
        if (t < o) { sb[t] += sb[t + o]; sq[t] += sq[t + o]; }
        __syncthreads();
    }
    if (t == 0) {
        float mu = sb[0] / NR;
        float var = sq[0] / NR - mu * mu;
        if (var < 0.f) var = 0.f;
        stats[h] = mu;
        stats[HID + h] = rsqrtf(var + 1e-5f);
    }
}

// ---------------------------------------------------------------- BatchNorm apply
__global__ void bn_apply(const void* __restrict__ r, const void* __restrict__ gamma,
                         const void* __restrict__ beta, const int* __restrict__ flags,
                         const float* __restrict__ stats,
                         float* __restrict__ rnorm, void* __restrict__ out_base) {
    const int fr = flags[1], fg = flags[14], fb = flags[15], fo = flags[0];
    int i = blockIdx.x * 256 + threadIdx.x;
    if (i >= NR * HID) return;
    int h = i & 127;
    float v = san((ldf(r, i, fr) - stats[h]) * stats[HID + h] * ldf(gamma, h, fg)
                  + ldf(beta, h, fb));
    rnorm[i] = v;
    stf(out_base, NN * HID + i, v, fo);
}

// ---------------------------------------------------------------- Rmb[rel,h] (bf16)
__global__ void rm_kernel(const void* __restrict__ Wmess, const void* __restrict__ bmess,
                          const int* __restrict__ flags,
                          const float* __restrict__ rnorm, bf16* __restrict__ Rmb) {
    __shared__ float rl[HID];
    const int fW = flags[6], fb = flags[7];
    int rel = blockIdx.x, h = threadIdx.x;
    rl[h] = rnorm[rel * HID + h];
    __syncthreads();
    float a = ldf(bmess, h, fb);
    for (int k = 0; k < HID; ++k)
        a += ldf(Wmess, h * 2 * HID + HID + k, fW) * rl[k];
    Rmb[rel * HID + h] = f2b(san(a));
}

// ================================================================ MFMA kernels
#define MLDA 136
#define SWST 68   // swred row stride in floats (64*68*4 = 17408 B == sizeof(ml))

__device__ __forceinline__ short8 load_bfrag(const void* W, int n, int k0, int f32) {
    short8 b;
    if (f32) {
        const float* Wf = (const float*)W + (size_t)n * 2 * HID + k0;
        float4 u0 = *(const float4*)Wf;
        float4 u1 = *(const float4*)(Wf + 4);
        b[0] = (short)bfbits(u0.x); b[1] = (short)bfbits(u0.y);
        b[2] = (short)bfbits(u0.z); b[3] = (short)bfbits(u0.w);
        b[4] = (short)bfbits(u1.x); b[5] = (short)bfbits(u1.y);
        b[6] = (short)bfbits(u1.z); b[7] = (short)bfbits(u1.w);
    } else {
        b = *(const short8*)((const bf16*)W + (size_t)n * 2 * HID + k0);
    }
    return b;
}

// ---------------------------------------------------------------- Xm = x @ Wmess[:, :128]^T (persistent)
__global__ __launch_bounds__(256, 4) void xm_mfma(const void* __restrict__ x,
                                                  const void* __restrict__ Wmess,
                                                  const int* __restrict__ flags,
                                                  bf16* __restrict__ Xmb) {
    __shared__ short ml[64 * MLDA];
    const int fx = flags[0], fW = flags[6];
    int tid = threadIdx.x;
    int l = tid & 63, w = tid >> 6;
    int quad = l >> 4, lo16 = l & 15;
    int nbase = w * 32;
    short8 bfr[2][4];
#pragma unroll
    for (int nt = 0; nt < 2; ++nt)
#pragma unroll
        for (int kk = 0; kk < 4; ++kk)
            bfr[nt][kk] = load_bfrag(Wmess, nbase + nt * 16 + lo16, kk * 32 + quad * 8, fW);

    const int ntiles = (NN + 63) / 64;
    for (int tile = blockIdx.x; tile < ntiles; tile += gridDim.x) {
        __syncthreads();
#pragma unroll
        for (int p = 0; p < 8; ++p) {
            int rl_ = p * 8 + (tid >> 5);
            int node = clampi(tile * 64 + rl_, NN);
            int k4 = (tid & 31) * 4;
            unsigned int o0, o1;
            if (fx) {
                float4 v = *(const float4*)((const float*)x + (size_t)node * HID + k4);
                o0 = packbf2(v.x, v.y);
                o1 = packbf2(v.z, v.w);
            } else {
                uint2 u = *(const uint2*)((const bf16*)x + (size_t)node * HID + k4);
                o0 = u.x; o1 = u.y;
            }
            unsigned int* dst = (unsigned int*)&ml[rl_ * MLDA + k4];
            dst[0] = o0; dst[1] = o1;
        }
        __syncthreads();
        float4_ acc[4][2];
#pragma unroll
        for (int mt = 0; mt < 4; ++mt)
#pragma unroll
            for (int nt = 0; nt < 2; ++nt)
                acc[mt][nt] = (float4_){0.f, 0.f, 0.f, 0.f};
#pragma unroll
        for (int kk = 0; kk < 4; ++kk) {
            short8 a[4];
#pragma unroll
            for (int mt = 0; mt < 4; ++mt)
                a[mt] = *(const short8*)&ml[(mt * 16 + lo16) * MLDA + kk * 32 + quad * 8];
#pragma unroll
            for (int mt = 0; mt < 4; ++mt)
#pragma unroll
                for (int nt = 0; nt < 2; ++nt)
                    acc[mt][nt] = __builtin_amdgcn_mfma_f32_16x16x32_bf16(
                        a[mt], bfr[nt][kk], acc[mt][nt], 0, 0, 0);
        }
#pragma unroll
        for (int mt = 0; mt < 4; ++mt)
#pragma unroll
            for (int nt = 0; nt < 2; ++nt)
#pragma unroll
                for (int r = 0; r < 4; ++r) {
                    int node = tile * 64 + mt * 16 + quad * 4 + r;
                    if (node < NN)
                        Xmb[node * HID + nbase + nt * 16 + lo16] = f2b(san(acc[mt][nt][r]));
                }
    }
}

// ---------------------------------------------------------------- edge logits: CSR-slot order, LDS-reduction epilogue
__global__ __launch_bounds__(256, 6) void edge_coeff_mfma(
        const bf16* __restrict__ Xmb, const bf16* __restrict__ Rmb,
        const void* __restrict__ Wmatt, const float* __restrict__ cmatt,
        const void* __restrict__ maw, const unsigned int* __restrict__ hrcsr,
        const int* __restrict__ flags, float* __restrict__ ccsr) {
    __shared__ short ml[64 * MLDA];     // staging tile; aliased as swred in epilogue
    const int fWm = flags[8], fmw = flags[10];
    int tid = threadIdx.x;
    int l = tid & 63, w = tid >> 6;
    int quad = l >> 4, lo16 = l & 15;
    int nbase = w * 32;
    short8 bfr[2][4];
#pragma unroll
    for (int nt = 0; nt < 2; ++nt)
#pragma unroll
        for (int kk = 0; kk < 4; ++kk)
            bfr[nt][kk] = load_bfrag(Wmatt, nbase + nt * 16 + lo16, kk * 32 + quad * 8, fWm);

    int n0 = nbase + lo16, n1 = n0 + 16;
    float c0 = cmatt[n0], c1 = cmatt[n1];
    float w0 = ldf(maw, n0, fmw), w1 = ldf(maw, n1, fmw);

    const int ntiles = (NE + 63) / 64;
    const int seg = tid & 15;
    const int rowsub = tid >> 4;
    float* swred = (float*)ml;
    for (int T = blockIdx.x; T < ntiles; T += gridDim.x) {
        __syncthreads();
#pragma unroll
        for (int p = 0; p < 4; ++p) {
            int el = p * 16 + rowsub;
            int slot = T * 64 + el;
            unsigned int hr = hrcsr[slot < NE ? slot : NE - 1];
            int head = hr & 0xffffu, rel = hr >> 16;
            int k8 = seg * 8;
            uint4 xv = *(const uint4*)&Xmb[head * HID + k8];
            uint4 rv = *(const uint4*)&Rmb[rel * HID + k8];
            uint4 o;
            o.x = packbf2(ftanh(bflo(xv.x) + bflo(rv.x)), ftanh(bfhi(xv.x) + bfhi(rv.x)));
            o.y = packbf2(ftanh(bflo(xv.y) + bflo(rv.y)), ftanh(bfhi(xv.y) + bfhi(rv.y)));
            o.z = packbf2(ftanh(bflo(xv.z) + bflo(rv.z)), ftanh(bfhi(xv.z) + bfhi(rv.z)));
            o.w = packbf2(ftanh(bflo(xv.w) + bflo(rv.w)), ftanh(bfhi(xv.w) + bfhi(rv.w)));
            *(uint4*)&ml[el * MLDA + k8] = o;
        }
        __syncthreads();
        float4_ acc[4][2];
#pragma unroll
        for (int mt = 0; mt < 4; ++mt)
#pragma unroll
            for (int nt = 0; nt < 2; ++nt)
                acc[mt][nt] = (float4_){0.f, 0.f, 0.f, 0.f};
#pragma unroll
        for (int kk = 0; kk < 4; ++kk) {
            short8 a[4];
#pragma unroll
            for (int mt = 0; mt < 4; ++mt)
                a[mt] = *(const short8*)&ml[(mt * 16 + lo16) * MLDA + kk * 32 + quad * 8];
#pragma unroll
            for (int mt = 0; mt < 4; ++mt)
#pragma unroll
                for (int nt = 0; nt < 2; ++nt)
                    acc[mt][nt] = __builtin_amdgcn_mfma_f32_16x16x32_bf16(
                        a[mt], bfr[nt][kk], acc[mt][nt], 0, 0, 0);
        }
        __syncthreads();   // all waves done READING ml before alias overwrite
#pragma unroll
        for (int mt = 0; mt < 4; ++mt)
#pragma unroll
            for (int r = 0; r < 4; ++r) {
                float z0 = acc[mt][0][r] + c0;
                z0 = fmaxf(z0, 0.f) + LRELU * fminf(z0, 0.f);
                float z1 = acc[mt][1][r] + c1;
                z1 = fmaxf(z1, 0.f) + LRELU * fminf(z1, 0.f);
                int row = mt * 16 + quad * 4 + r;
                swred[row * SWST + w * 16 + lo16] = w0 * z0 + w1 * z1;
            }
        __syncthreads();
        if (tid < 64) {
            int slot = T * 64 + tid;
            if (slot < NE) {
                const float4* rp = (const float4*)&swred[tid * SWST];
                float4 s4 = rp[0];
#pragma unroll
                for (int q = 1; q < 16; ++q) {
                    float4 v = rp[q];
                    s4.x += v.x; s4.y += v.y; s4.z += v.z; s4.w += v.w;
                }
                ccsr[slot] = san(s4.x + s4.y + s4.z + s4.w);
            }
        }
    }
}

// ---------------------------------------------------------------- fused aggregation + gate (persistent)
__global__ __launch_bounds__(256, 4) void aggr_gate(
        const void* __restrict__ x, const bf16* __restrict__ Xmb,
        const bf16* __restrict__ Rmb,
        const int* __restrict__ offs, const unsigned int* __restrict__ hrcsr,
        const float* __restrict__ ccsr,
        const void* __restrict__ Wxatt, const float* __restrict__ cxatt,
        const void* __restrict__ xaw, const int* __restrict__ flags,
        void* __restrict__ outx) {
    __shared__ short ml[64 * MLDA];
    __shared__ float swave[4][64];
    __shared__ float lgL[64];
    const int fx = flags[0], fWx = flags[11], fxw = flags[13], fo = flags[0];
    int tid = threadIdx.x;
    int l = tid & 63, w = tid >> 6;
    int quad = l >> 4, lo16 = l & 15;
    int nbase = w * 32;
    short8 bfr[2][4];
#pragma unroll
    for (int nt = 0; nt < 2; ++nt)
#pragma unroll
        for (int kk = 0; kk < 4; ++kk)
            bfr[nt][kk] = load_bfrag(Wxatt, nbase + nt * 16 + lo16, kk * 32 + quad * 8, fWx);

    int n0 = nbase + lo16, n1 = n0 + 16;
    float c0 = cxatt[n0], c1 = cxatt[n1];
    float w0 = ldf(xaw, n0, fxw), w1 = ldf(xaw, n1, fxw);

    const int ntiles = (NN + 31) / 32;
    for (int tile = blockIdx.x; tile < ntiles; tile += gridDim.x) {
        __syncthreads();
        // stage x rows (even rows 2j)
#pragma unroll
        for (int p = 0; p < 4; ++p) {
            int j = p * 8 + (tid >> 5);
            int node = clampi(tile * 32 + j, NN);
            int k4 = (tid & 31) * 4;
            unsigned int o0, o1;
            if (fx) {
                float4 v = *(const float4*)((const float*)x + (size_t)node * HID + k4);
                o0 = packbf2(v.x, v.y);
                o1 = packbf2(v.z, v.w);
            } else {
                uint2 u = *(const uint2*)((const bf16*)x + (size_t)node * HID + k4);
                o0 = u.x; o1 = u.y;
            }
            unsigned int* dst = (unsigned int*)&ml[(2 * j) * MLDA + k4];
            dst[0] = o0; dst[1] = o1;
        }
        // aggregate sum_mess into odd rows (2j+1): wave w handles nodes w*8..w*8+7
        const int col = l * 2;
#pragma unroll 1
        for (int jj = 0; jj < 8; ++jj) {
            int j = w * 8 + jj;
            int node = tile * 32 + j;
            unsigned int out = 0;
            if (node < NN) {
                int s = offs[node], en = offs[node + 1];
                float m = -INFINITY;
                for (int i = s + l; i < en; i += 64) m = fmaxf(m, ccsr[i]);
                m = waveMax(m);
                float lsum = 0.f;
                for (int i = s + l; i < en; i += 64) lsum += __expf(ccsr[i] - m);
                lsum = waveSum(lsum);
                float inv = 1.f / (lsum + 1e-16f);
                float acc0 = 0.f, acc1 = 0.f;
                int i = s;
                for (; i + 2 <= en; i += 2) {
                    unsigned int hr0 = hrcsr[i], hr1 = hrcsr[i + 1];
                    float wg0 = __expf(ccsr[i] - m), wg1 = __expf(ccsr[i + 1] - m);
                    unsigned int xv0 = *(const unsigned int*)&Xmb[(hr0 & 0xffffu) * HID + col];
                    unsigned int rv0 = *(const unsigned int*)&Rmb[(hr0 >> 16) * HID + col];
                    unsigned int xv1 = *(const unsigned int*)&Xmb[(hr1 & 0xffffu) * HID + col];
                    unsigned int rv1 = *(const unsigned int*)&Rmb[(hr1 >> 16) * HID + col];
                    acc0 += wg0 * ftanh(bflo(xv0) + bflo(rv0)) + wg1 * ftanh(bflo(xv1) + bflo(rv1));
                    acc1 += wg0 * ftanh(bfhi(xv0) + bfhi(rv0)) + wg1 * ftanh(bfhi(xv1) + bfhi(rv1));
                }
                if (i < en) {
                    unsigned int hr0 = hrcsr[i];
                    float wg0 = __expf(ccsr[i] - m);
                    unsigned int xv0 = *(const unsigned int*)&Xmb[(hr0 & 0xffffu) * HID + col];
                    unsigned int rv0 = *(const unsigned int*)&Rmb[(hr0 >> 16) * HID + col];
                    acc0 += wg0 * ftanh(bflo(xv0) + bflo(rv0));
                    acc1 += wg0 * ftanh(bfhi(xv0) + bfhi(rv0));
                }
                out = packbf2(san(acc0 * inv), san(acc1 * inv));
            }
            *(unsigned int*)&ml[(2 * j + 1) * MLDA + col] = out;
        }
        __syncthreads();
        float4_ acc[4][2];
#pragma unroll
        for (int mt = 0; mt < 4; ++mt)
#pragma unroll
            for (int nt = 0; nt < 2; ++nt)
                acc[mt][nt] = (float4_){0.f, 0.f, 0.f, 0.f};
#pragma unroll
        for (int kk = 0; kk < 4; ++kk) {
            short8 a[4];
#pragma unroll
            for (int mt = 0; mt < 4; ++mt)
                a[mt] = *(const short8*)&ml[(mt * 16 + lo16) * MLDA + kk * 32 + quad * 8];
#pragma unroll
            for (int mt = 0; mt < 4; ++mt)
#pragma unroll
                for (int nt = 0; nt < 2; ++nt)
                    acc[mt][nt] = __builtin_amdgcn_mfma_f32_16x16x32_bf16(
                        a[mt], bfr[nt][kk], acc[mt][nt], 0, 0, 0);
        }
#pragma unroll
        for (int mt = 0; mt < 4; ++mt)
#pragma unroll
            for (int r = 0; r < 4; ++r) {
                float z0 = acc[mt][0][r] + c0;
                z0 = fmaxf(z0, 0.f) + LRELU * fminf(z0, 0.f);
                float z1 = acc[mt][1][r] + c1;
                z1 = fmaxf(z1, 0.f) + LRELU * fminf(z1, 0.f);
                float s = w0 * z0 + w1 * z1;
                s = xorReduce16(s);
                if (lo16 == 0) swave[w][mt * 16 + quad * 4 + r] = s;
            }
        __syncthreads();
        if (tid < 64)
            lgL[tid] = san(swave[0][tid] + swave[1][tid] + swave[2][tid] + swave[3][tid]);
        __syncthreads();
        // combine: out = softmax(lg[2n], lg[2n+1]) · (x, sum_mess)
#pragma unroll
        for (int it = 0; it < 16; ++it) {
            int idx = tid + 256 * it;
            int nl = idx >> 7, h = idx & 127;
            int node = tile * 32 + nl;
            if (node < NN) {
                float g0 = lgL[2 * nl], g1 = lgL[2 * nl + 1];
                float mm = fmaxf(g0, g1);
                float e0 = __expf(g0 - mm), e1 = __expf(g1 - mm);
                float inv = __builtin_amdgcn_rcpf(e0 + e1);
                float xv = ldf(x, node * HID + h, fx);
                float sv = b2f(((const bf16*)ml)[(2 * nl + 1) * MLDA + h]);
                stf(outx, node * HID + h, san((e0 * xv + e1 * sv) * inv), fo);
            }
        }
    }
}

// ---------------------------------------------------------------- CSR build
__global__ void count_kernel(const int* __restrict__ ei, const int* __restrict__ flags,
                             int* __restrict__ counts) {
    const int is64e = flags[4];
    for (int e = blockIdx.x * blockDim.x + threadIdx.x; e < NE; e += gridDim.x * blockDim.x) {
        int tail = clampi(idx_at(ei, NE + e, is64e), NN);
        atomicAdd(&counts[tail], 1);
    }
}

__global__ void scan_phase1(const int* __restrict__ counts, int* __restrict__ offs,
                            int* __restrict__ bsum) {
    __shared__ int buf[256];
    int t = threadIdx.x;
    int i = blockIdx.x * 256 + t;
    int v = (i < NN) ? counts[i] : 0;
    buf[t] = v;
    __syncthreads();
    for (int off = 1; off < 256; off <<= 1) {
        int add = (t >= off) ? buf[t - off] : 0;
        __syncthreads();
        buf[t] += add;
        __syncthreads();
    }
    if (i < NN) offs[i] = buf[t] - v;
    if (t == 255) bsum[blockIdx.x] = buf[255];
}

__global__ void scan_phase2(int* __restrict__ bsum, int* __restrict__ bexc) {
    __shared__ int buf[256];
    int t = threadIdx.x;
    int v = (t < SCAN_BLOCKS) ? bsum[t] : 0;
    buf[t] = v;
    __syncthreads();
    for (int off = 1; off < 256; off <<= 1) {
        int add = (t >= off) ? buf[t - off] : 0;
        __syncthreads();
        buf[t] += add;
        __syncthreads();
    }
    if (t < SCAN_BLOCKS) bexc[t] = buf[t] - v;
    if (t == 255) bexc[SCAN_BLOCKS] = buf[255];
}

__global__ void scan_phase3(int* __restrict__ offs, int* __restrict__ cursor,
                            const int* __restrict__ bexc) {
    int i = blockIdx.x * 256 + threadIdx.x;
    if (i < NN) {
        int v = offs[i] + bexc[blockIdx.x];
        offs[i] = v;
        cursor[i] = v;
    }
    if (i == 0) offs[NN] = bexc[SCAN_BLOCKS];
}

__global__ void scatter_kernel(const int* __restrict__ ei, const int* __restrict__ ea,
                               const int* __restrict__ flags,
                               int* __restrict__ cursor, unsigned int* __restrict__ hrcsr) {
    const int is64e = flags[4], is64a = flags[5];
    for (int e = blockIdx.x * blockDim.x + threadIdx.x; e < NE; e += gridDim.x * blockDim.x) {
        int tail = clampi(idx_at(ei, NE + e, is64e), NN);
        int head = clampi(idx_at(ei, e, is64e), NN);
        int rel = clampi(idx_at(ea, e, is64a), NR);
        int p = atomicAdd(&cursor[tail], 1);
        if (p >= 0 && p < NE)
            hrcsr[p] = (unsigned int)head | ((unsigned int)rel << 16);
    }
}

extern "C" void kernel_launch(void* const* d_in, const int* in_sizes, int n_in,
                              void* d_out, int out_size, void* d_ws, size_t ws_size,
                              hipStream_t stream) {
    const void* x     = d_in[0];
    const void* r     = d_in[1];
    const void* qc    = d_in[2];
    const void* fq    = d_in[3];
    const int*  ei    = (const int*)d_in[4];
    const int*  ea    = (const int*)d_in[5];
    const void* Wmess = d_in[6];
    const void* bmess = d_in[7];
    const void* Wmatt = d_in[8];
    const void* bmatt = d_in[9];
    const void* maw   = d_in[10];
    const void* Wxatt = d_in[11];
    const void* bxatt = d_in[12];
    const void* xaw   = d_in[13];
    const void* gamma = d_in[14];
    const void* beta  = d_in[15];

    int*          flags  = (int*)d_ws;                       // 16
    int*          counts = flags + 16;                       // NN
    int*          offs   = counts + NN;                      // NN+1
    int*          cursor = offs + NN + 1;                    // NN (+3 pad)
    int*          bsum   = cursor + NN + 3;                  // 256
    int*          bexc   = bsum + 256;                       // 256+1 (+3 pad)
    unsigned int* hrcsr  = (unsigned int*)(bexc + 260);      // NE
    float*        ccsr   = (float*)(hrcsr + NE);             // NE
    float*        rnorm  = ccsr + NE;                        // NR*HID
    float*        stats  = rnorm + (size_t)NR * HID;         // 2*HID
    float*        cmatt  = stats + 2 * HID;                  // HID
    float*        cxatt  = cmatt + HID;                      // HID
    bf16*         Rmb    = (bf16*)(cxatt + HID);             // NR*HID
    bf16*         Xmb    = Rmb + (size_t)NR * HID;           // NN*HID

    hipMemsetAsync(counts, 0, NN * sizeof(int), stream);

    DetectArr da;
    const void* ps[16] = {x, r, qc, fq, ei, ea, Wmess, bmess, Wmatt, bmatt, maw,
                          Wxatt, bxatt, xaw, gamma, beta};
    int szs[16] = {NN * HID, NR * HID, HID, HID, 2 * NE, NE, 2 * HID * HID, HID,
                   2 * HID * HID, HID, HID, 2 * HID * HID, HID, HID, HID, HID};
    for (int i = 0; i < 16; ++i) {
        da.p[i] = ps[i];
        da.sz[i] = szs[i];
        da.kind[i] = (i == 4 || i == 5) ? 1 : 0;
    }
    detect_all<<<16, 64, 0, stream>>>(da, flags);

    bn_pre<<<HID + 1, 256, 0, stream>>>(r, flags, stats, Wmatt, bmatt, qc,
                                        Wxatt, bxatt, fq, cmatt, cxatt);
    bn_apply<<<(NR * HID + 255) / 256, 256, 0, stream>>>(r, gamma, beta, flags, stats,
                                                         rnorm, d_out);
    rm_kernel<<<NR, HID, 0, stream>>>(Wmess, bmess, flags, rnorm, Rmb);
    xm_mfma<<<512, 256, 0, stream>>>(x, Wmess, flags, Xmb);
    count_kernel<<<1024, 256, 0, stream>>>(ei, flags, counts);
    scan_phase1<<<SCAN_BLOCKS, 256, 0, stream>>>(counts, offs, bsum);
    scan_phase2<<<1, 256, 0, stream>>>(bsum, bexc);
    scan_phase3<<<SCAN_BLOCKS, 256, 0, stream>>>(offs, cursor, bexc);
    scatter_kernel<<<1024, 256, 0, stream>>>(ei, ea, flags, cursor, hrcsr);
    edge_coeff_mfma<<<1536, 256, 0, stream>>>(Xmb, Rmb, Wmatt, cmatt, maw, hrcsr, flags,
                                              ccsr);
    aggr_gate<<<1024, 256, 0, stream>>>(x, Xmb, Rmb, offs, hrcsr, ccsr,
                                        Wxatt, cxatt, xaw, flags, d_out);
}